// Round 8
// baseline (4404.453 us; speedup 1.0000x reference)
//
#include <hip/hip_runtime.h>
#include <math.h>

// latentODE: T=200, B=1024, D=128, T_OBS=140, L=20, LAT=32, GRU_U=200, UNITS=100
// R7:  1024blk x 2 waves, K-half, 182 wt/lane, readlane bcast, 3 barriers = 1203us (best).
// R8:  6 barriers -> barrier-bound 1645us. R9: cap-170 bounds -> SCRATCH = 1826us.
// R10: 2 batches/block amortize -> no better (1404); enc tanh_fast -290us (keep).
// Cross-round law: per-CU per-batch-eval ~900-1400cyc in ALL designs; R7 simplest+best.
// R11: R7 structure, 3-way K-split: 1024blk x 192thr (3 waves), 124 wt/lane
//      (11x2+34x2+34), total ~164 regs -> 3 waves/SIMD possible, 4 blk/CU, one
//      round. bounds(192,2) = cap 256, NO scratch risk (R9 lesson). Same 3
//      barriers/eval, literal-idx readlane per wave-uniform branch.
#define BB 1024
#define DD 128
#define NWG 256
#define CH 28
#define NCH 5

// ws layout (float offsets)
#define WS_WPACK 0
#define WS_B1E   81920
#define WS_W1Y   82560
#define WS_Y     106560
#define WS_Z     147520
#define WS_HPRE  180288
#define WS_SOL   180288

__device__ __forceinline__ float bcast(float v, int lane) {
    return __uint_as_float(__builtin_amdgcn_readlane(__float_as_uint(v), lane));
}

// tanh(x) = 1 - 2/(e^{2x}+1); exp2/rcp HW approx (~1ulp), saturates correctly.
__device__ __forceinline__ float tanh_fast(float x) {
    const float t = __builtin_amdgcn_exp2f(x * 2.88539008177793f);
    return 1.f - 2.f * __builtin_amdgcn_rcpf(t + 1.f);
}
// sigmoid(x) = 1/(1+e^-x), exp2/rcp form; saturates to {0,1} correctly.
__device__ __forceinline__ float sigm_fast(float x) {
    const float t = __builtin_amdgcn_exp2f(x * -1.4426950408889634f);
    return __builtin_amdgcn_rcpf(1.f + t);
}

__global__ __launch_bounds__(256) void prep_kernel(
    const float* __restrict__ uw1, const float* __restrict__ ub1,
    const float* __restrict__ rw1, const float* __restrict__ rb1,
    const float* __restrict__ nw1, const float* __restrict__ nb1,
    float* __restrict__ ws)
{
    int tid = blockIdx.x * blockDim.x + threadIdx.x;
    int nth = gridDim.x * blockDim.x;
    for (int idx = tid; idx < 128 * 640; idx += nth) {
        int k = idx / 640, j = idx - k * 640;
        float v = 0.f;
        if (j < 600) {
            int g = j / 200, jj = j - g * 200;
            const float* w1 = (g == 0) ? uw1 : (g == 1) ? rw1 : nw1;
            v = w1[(40 + k) * 200 + jj];
        }
        ws[WS_WPACK + idx] = v;
    }
    for (int j = tid; j < 640; j += nth) {
        float s = 0.f;
        if (j < 600) {
            int g = j / 200, jj = j - g * 200;
            const float* w1 = (g == 0) ? uw1 : (g == 1) ? rw1 : nw1;
            const float* b1 = (g == 0) ? ub1 : (g == 1) ? rb1 : nb1;
            s = b1[jj];
            for (int k = 168; k < 296; ++k) s += w1[k * 200 + jj];
        }
        ws[WS_B1E + j] = s;
    }
    for (int idx = tid; idx < 40 * 600; idx += nth) {
        int k = idx / 600, j = idx - k * 600;
        int g = j / 200, jj = j - g * 200;
        const float* w1 = (g == 0) ? uw1 : (g == 1) ? rw1 : nw1;
        ws[WS_W1Y + idx] = w1[k * 200 + jj];
    }
}

__global__ __launch_bounds__(256) void hpre_gemm(
    const float* __restrict__ truth, const int* __restrict__ obs_idx,
    const float* __restrict__ ws, float* __restrict__ hpre, int s0)
{
    __shared__ float sx[64][68];
    __shared__ float sw[64][132];
    const int t0 = threadIdx.x;
    const int jt = blockIdx.x % 5;
    const int bt = (blockIdx.x / 5) % 16;
    const int sl = blockIdx.x / 80;
    const int oi = obs_idx[139 - (s0 + sl)];
    const int b0 = bt * 64;
    const float* wpack = ws + WS_WPACK;
    const float* b1e   = ws + WS_B1E;

    const int jj  = t0 & 15;
    const int bb4 = t0 >> 4;
    float acc[8][4];
#pragma unroll
    for (int m = 0; m < 8; ++m)
#pragma unroll
        for (int q = 0; q < 4; ++q) acc[m][q] = 0.f;

    for (int kh = 0; kh < 2; ++kh) {
        __syncthreads();
        for (int i = t0; i < 64 * 16; i += 256) {
            int bb = i >> 4, kq = i & 15;
            const float4 v = *(const float4*)&truth[((size_t)oi * BB + b0 + bb) * DD + kh * 64 + kq * 4];
            *(float4*)&sx[bb][kq * 4] = v;
        }
        for (int i = t0; i < 64 * 32; i += 256) {
            int kk = i >> 5, jq = i & 31;
            const float4 v = *(const float4*)&wpack[(kh * 64 + kk) * 640 + jt * 128 + jq * 4];
            *(float4*)&sw[kk][jq * 4] = v;
        }
        __syncthreads();
#pragma unroll 4
        for (int k = 0; k < 64; ++k) {
            float xv[4], wv[8];
#pragma unroll
            for (int q = 0; q < 4; ++q) xv[q] = sx[bb4 * 4 + q][k];
#pragma unroll
            for (int m = 0; m < 8; ++m) wv[m] = sw[k][jj + 16 * m];
#pragma unroll
            for (int m = 0; m < 8; ++m)
#pragma unroll
                for (int q = 0; q < 4; ++q) acc[m][q] += wv[m] * xv[q];
        }
    }
    const int bblk = bt * 16 + bb4;
#pragma unroll
    for (int m = 0; m < 8; ++m) {
        int j = jt * 128 + jj + 16 * m;
        if (j < 600) {
            float be = b1e[j];
#pragma unroll
            for (int q = 0; q < 4; ++q)
                hpre[(size_t)((sl * 256 + bblk) * 4 + q) * 600 + j] = acc[m][q] + be;
        }
    }
}

__global__ __launch_bounds__(256, 1) void enc_chunk(
    const float* __restrict__ tg, const int* __restrict__ obs_idx,
    const float* __restrict__ eps,
    const float* __restrict__ ew1, const float* __restrict__ eb1,
    const float* __restrict__ ew2, const float* __restrict__ eb2,
    const float* __restrict__ uw2, const float* __restrict__ ub2,
    const float* __restrict__ rw2, const float* __restrict__ rb2,
    const float* __restrict__ nw2, const float* __restrict__ nb2,
    const float* __restrict__ z0w1, const float* __restrict__ z0b1,
    const float* __restrict__ z0w2, const float* __restrict__ z0b2,
    float* __restrict__ ws, int s0)
{
    __shared__ float s_t[200];
    __shared__ int   s_oi[140];
    __shared__ __align__(16) float s_y[40][4];      // [k][b]
    __shared__ __align__(16) float s_ytmp[20][4];
    __shared__ float s_kacc[20][4];
    __shared__ __align__(16) float s_hid[4][104];   // pads 100..103 = 0
    __shared__ float s_pe[20][4][2];
    __shared__ __align__(16) float s_ew1t[100 * 20];   // [c][k]
    __shared__ __align__(16) float s_w2n[40 * 212];    // [o][k], k>=200 zero
    __shared__ __align__(16) float s_hur[4][416];      // u: [0..207], r: [208..415]
    __shared__ __align__(16) float s_hn[4][208];       // pads 200..207 = 0
    __shared__ float s_pw[80][4][4];
    __shared__ float s_pn[40][4][4];
    __shared__ float s_u[40][4];
    __shared__ __align__(16) float s_yr[40][4];
    __shared__ float s_z0o[4][64];

    const int t0 = threadIdx.x;
    const int bblk = blockIdx.x;
    const int b0 = bblk * 4;
    const float* hpre = ws + WS_HPRE;

    // ---- register weights (roles; worst-case union ~280 VGPR, fits (256,1)) ----
    float rgy[3][40];     // t<200: W1y cols {u_j, r_j, n_j}
    float rew2h[52];      // t<160: RK stage2 K-half
    float rw2q[2][52];    // t<160: W2 u/r quarter, two outs same gate
    float eb1_r = 0.f, eb2_r = 0.f, bur_r = 0.f, bn_r = 0.f;

    if (t0 < 200) {
#pragma unroll
        for (int g = 0; g < 3; ++g)
#pragma unroll
            for (int k = 0; k < 40; ++k)
                rgy[g][k] = ws[WS_W1Y + k * 600 + g * 200 + t0];
    }
    if (t0 < 100) eb1_r = eb1[t0];
    if (t0 < 160) {
        const int c2 = t0 % 20, kh = t0 / 80;
#pragma unroll
        for (int i = 0; i < 52; ++i) {
            const int row = kh * 52 + i;
            rew2h[i] = (row < 100) ? ew2[row * 20 + c2] : 0.f;
        }
    }
    if (t0 < 80) eb2_r = eb2[t0 % 20];
    if (t0 < 160) {
        const int p = t0 % 20, g = (t0 / 20) % 2, kq = t0 / 40;
        const float* w2 = g ? rw2 : uw2;
#pragma unroll
        for (int j = 0; j < 2; ++j)
#pragma unroll
            for (int i = 0; i < 52; ++i) {
                const int row = kq * 52 + i;
                rw2q[j][i] = (row < 200) ? w2[row * 40 + p + 20 * j] : 0.f;
            }
        bur_r = ((t0 % 80) < 40) ? ub2[t0 % 80] : rb2[(t0 % 80) - 40];
        bn_r = nb2[t0 % 40];
    }

    for (int i = t0; i < 2000; i += 256) { int k = i / 100, c = i % 100; s_ew1t[c * 20 + k] = ew1[i]; }
    for (int i = t0; i < 40 * 212; i += 256) { int o = i / 212, k = i % 212; s_w2n[i] = (k < 200) ? nw2[k * 40 + o] : 0.f; }
    for (int i = t0; i < 200; i += 256) s_t[i] = tg[i];
    for (int i = t0; i < 140; i += 256) s_oi[i] = obs_idx[i];
    if (t0 < 160) { int k = t0 % 40, b = t0 / 40; s_y[k][b] = s0 ? ws[WS_Y + k * 1024 + b0 + b] : 0.f; }
    if (t0 < 4) {
#pragma unroll
        for (int i = 0; i < 4; ++i) s_hid[t0][100 + i] = 0.f;
#pragma unroll
        for (int i = 0; i < 8; ++i) { s_hur[t0][200 + i] = 0.f; s_hur[t0][408 + i] = 0.f; s_hn[t0][200 + i] = 0.f; }
    }
    __syncthreads();

    for (int sl = 0; sl < CH; ++sl) {
        const int s = s0 + sl;
        const int oi = s_oi[139 - s];
        const float dt = (s == 0) ? 0.f : (s_t[oi] - s_t[s_oi[140 - s]]);

        float hpu[4], hpr[4], hpn[4];
        if (t0 < 200) {
#pragma unroll
            for (int q = 0; q < 4; ++q) {
                const size_t r = (size_t)((sl * 256 + bblk) * 4 + q) * 600;
                hpu[q] = hpre[r + t0];
                hpr[q] = hpre[r + 200 + t0];
                hpn[q] = hpre[r + 400 + t0];
            }
        }

        // ---- RK4 on ym (enc_f: 20 -> 100 -> 20) ----
#pragma unroll 1
        for (int e = 0; e < 4; ++e) {
            if (t0 < 100) {
                const int c = t0;
                float a[4] = {eb1_r, eb1_r, eb1_r, eb1_r};
#pragma unroll
                for (int i = 0; i < 5; ++i) {
                    const float4 wv = *(const float4*)&s_ew1t[c * 20 + 4 * i];
                    const float wk[4] = {wv.x, wv.y, wv.z, wv.w};
#pragma unroll
                    for (int kk = 0; kk < 4; ++kk) {
                        const int k = 4 * i + kk;
                        const float4 yv = (e == 0) ? *(const float4*)&s_y[k][0]
                                                   : *(const float4*)&s_ytmp[k][0];
                        a[0] += wk[kk] * yv.x; a[1] += wk[kk] * yv.y;
                        a[2] += wk[kk] * yv.z; a[3] += wk[kk] * yv.w;
                    }
                }
#pragma unroll
                for (int b = 0; b < 4; ++b) s_hid[b][c] = tanh_fast(a[b]);
            }
            __syncthreads();
            if (t0 < 160) {
                const int c2 = t0 % 20, b = (t0 / 20) % 4, kh = t0 / 80;
                float acc = 0.f;
#pragma unroll
                for (int i = 0; i < 13; ++i) {
                    const float4 hv = *(const float4*)&s_hid[b][kh * 52 + 4 * i];
                    acc += hv.x * rew2h[4 * i] + hv.y * rew2h[4 * i + 1]
                         + hv.z * rew2h[4 * i + 2] + hv.w * rew2h[4 * i + 3];
                }
                s_pe[c2][b][kh] = acc;
            }
            __syncthreads();
            if (t0 < 80) {
                const int c2 = t0 % 20, b = t0 / 20;
                const float kv = eb2_r + s_pe[c2][b][0] + s_pe[c2][b][1];
                const float y0 = s_y[c2][b];
                if (e == 0)      { s_kacc[c2][b] = kv;        s_ytmp[c2][b] = y0 + 0.5f * dt * kv; }
                else if (e == 1) { s_kacc[c2][b] += 2.f * kv; s_ytmp[c2][b] = y0 + 0.5f * dt * kv; }
                else if (e == 2) { s_kacc[c2][b] += 2.f * kv; s_ytmp[c2][b] = y0 + dt * kv; }
                else             { s_y[c2][b] = y0 + (dt / 6.f) * (s_kacc[c2][b] + kv); }
            }
            __syncthreads();
        }

        // ---- B: u/r hidden = tanh(hpre + y @ W1y) ----
        if (t0 < 200) {
            float au[4], ar[4];
#pragma unroll
            for (int b = 0; b < 4; ++b) { au[b] = hpu[b]; ar[b] = hpr[b]; }
#pragma unroll
            for (int k = 0; k < 40; ++k) {
                const float4 yv = *(const float4*)&s_y[k][0];
                const float wu = rgy[0][k], wr = rgy[1][k];
                au[0] += wu * yv.x; au[1] += wu * yv.y; au[2] += wu * yv.z; au[3] += wu * yv.w;
                ar[0] += wr * yv.x; ar[1] += wr * yv.y; ar[2] += wr * yv.z; ar[3] += wr * yv.w;
            }
#pragma unroll
            for (int b = 0; b < 4; ++b) {
                s_hur[b][t0] = tanh_fast(au[b]);
                s_hur[b][208 + t0] = tanh_fast(ar[b]);
            }
        }
        __syncthreads();

        // ---- W2 u/r partials: (p,g,kq) -> outs {g_p, g_{p+20}}, K-quarter ----
        if (t0 < 160) {
            const int p = t0 % 20, g = (t0 / 20) % 2, kq = t0 / 40;
            const int goff = g * 208;
            float a1[4] = {0.f, 0.f, 0.f, 0.f}, a2[4] = {0.f, 0.f, 0.f, 0.f};
#pragma unroll
            for (int i = 0; i < 13; ++i) {
                const float wa = rw2q[0][4 * i], wb = rw2q[0][4 * i + 1],
                            wc = rw2q[0][4 * i + 2], wd = rw2q[0][4 * i + 3];
                const float we = rw2q[1][4 * i], wf = rw2q[1][4 * i + 1],
                            wg = rw2q[1][4 * i + 2], wh = rw2q[1][4 * i + 3];
#pragma unroll
                for (int b = 0; b < 4; ++b) {
                    const float4 hv = *(const float4*)&s_hur[b][goff + kq * 52 + 4 * i];
                    a1[b] += hv.x * wa + hv.y * wb + hv.z * wc + hv.w * wd;
                    a2[b] += hv.x * we + hv.y * wf + hv.z * wg + hv.w * wh;
                }
            }
            const int o1 = 40 * g + p, o2 = o1 + 20;
#pragma unroll
            for (int b = 0; b < 4; ++b) { s_pw[o1][b][kq] = a1[b]; s_pw[o2][b][kq] = a2[b]; }
        }
        __syncthreads();

        // ---- u/r reduce: sigmoid; u and yr = y*r ----
        if (t0 < 160) {
            const int o = t0 % 80, bp = t0 / 80;
#pragma unroll
            for (int j = 0; j < 2; ++j) {
                const int b = 2 * bp + j;
                const float v = bur_r + s_pw[o][b][0] + s_pw[o][b][1] + s_pw[o][b][2] + s_pw[o][b][3];
                const float sg = sigm_fast(v);
                if (o < 40) s_u[o][b] = sg;
                else        s_yr[o - 40][b] = s_y[o - 40][b] * sg;
            }
        }
        __syncthreads();

        // ---- C: n hidden = tanh(hpre_n + yr @ W1ny) ----
        if (t0 < 200) {
            float an[4];
#pragma unroll
            for (int b = 0; b < 4; ++b) an[b] = hpn[b];
#pragma unroll
            for (int k = 0; k < 40; ++k) {
                const float4 yv = *(const float4*)&s_yr[k][0];
                const float w = rgy[2][k];
                an[0] += w * yv.x; an[1] += w * yv.y; an[2] += w * yv.z; an[3] += w * yv.w;
            }
#pragma unroll
            for (int b = 0; b < 4; ++b) s_hn[b][t0] = tanh_fast(an[b]);
        }
        __syncthreads();

        // ---- W2n partials (weights from LDS, stride 212 = 4*odd) ----
        if (t0 < 160) {
            const int o = t0 % 40, kq = t0 / 40;
            float an[4] = {0.f, 0.f, 0.f, 0.f};
#pragma unroll
            for (int i = 0; i < 13; ++i) {
                const float4 wv = *(const float4*)&s_w2n[o * 212 + kq * 52 + 4 * i];
#pragma unroll
                for (int b = 0; b < 4; ++b) {
                    const float4 hv = *(const float4*)&s_hn[b][kq * 52 + 4 * i];
                    an[b] += hv.x * wv.x + hv.y * wv.y + hv.z * wv.z + hv.w * wv.w;
                }
            }
#pragma unroll
            for (int b = 0; b < 4; ++b) s_pn[o][b][kq] = an[b];
        }
        __syncthreads();

        // ---- n reduce + state update ----
        if (t0 < 160) {
            const int o = t0 % 40, b = t0 / 40;
            const float v = bn_r + s_pn[o][b][0] + s_pn[o][b][1] + s_pn[o][b][2] + s_pn[o][b][3];
            const float cand = (o < 20) ? v : fabsf(v);
            const float uu = s_u[o][b];
            s_y[o][b] = (1.f - uu) * cand + uu * s_y[o][b];
        }
        __syncthreads();
    }

    // ---- z0 head (last chunk) ----
    if (s0 + CH == 140) {
        if (t0 < 100) {
            const int c = t0;
            float a[4] = {z0b1[c], z0b1[c], z0b1[c], z0b1[c]};
#pragma unroll
            for (int k = 0; k < 40; ++k) {
                const float4 yv = *(const float4*)&s_y[k][0];
                const float w = z0w1[k * 100 + c];
                a[0] += w * yv.x; a[1] += w * yv.y; a[2] += w * yv.z; a[3] += w * yv.w;
            }
#pragma unroll
            for (int b = 0; b < 4; ++b) s_hid[b][c] = tanh_fast(a[b]);
        }
        __syncthreads();
        {
            const int b = t0 / 64, u = t0 % 64;
            float acc = z0b2[u];
#pragma unroll
            for (int i = 0; i < 25; ++i) {
                const float4 hv = *(const float4*)&s_hid[b][4 * i];
                acc += hv.x * z0w2[(4 * i) * 64 + u] + hv.y * z0w2[(4 * i + 1) * 64 + u]
                     + hv.z * z0w2[(4 * i + 2) * 64 + u] + hv.w * z0w2[(4 * i + 3) * 64 + u];
            }
            s_z0o[b][u] = acc;
        }
        __syncthreads();
        if (t0 < 128) {
            const int b = t0 / 32, i = t0 % 32;
            const int gb = b0 + b;
            ws[WS_Z + gb * 32 + i] = s_z0o[b][i] + eps[gb * 32 + i] * fabsf(s_z0o[b][32 + i]);
        }
    }
    if (t0 < 160) {
        const int k = t0 % 40, b = t0 / 40;
        ws[WS_Y + k * 1024 + b0 + b] = s_y[k][b];
    }
}

// R11 dec: 1024 blocks x 192 threads (3 waves), ONE BATCH PER BLOCK, 3-way
// K-split (R7 structure). Wave w rows: P1 {0-10,11-21,22-31}; P2/P3
// {0-33,34-66,67-99}. Lane l owns h1/h2 cols {l, 64+l} (l<36). Weights 124
// floats/lane -> ~164 total regs; bounds(192,2) cap 256 = NO scratch (R9
// lesson); natural allocation permits 3 waves/SIMD -> 4 blk/CU, one round.
// 3 barriers/eval; readlane with literal idx inside wave-uniform branches;
// RK state dup'd in all lanes (no LDS for z).
__global__ __launch_bounds__(192, 2) void dec_kernel(
    const float* __restrict__ tg,
    const float* __restrict__ dw1, const float* __restrict__ db1,
    const float* __restrict__ dw2, const float* __restrict__ db2,
    const float* __restrict__ dw3, const float* __restrict__ db3,
    float* __restrict__ ws)
{
    __shared__ float s_t[200];
    __shared__ float s_p1[3][100];
    __shared__ float s_p2[3][100];
    __shared__ float s_p3[3][32];

    const int t0 = threadIdx.x;
    const int w  = t0 / 64;          // wave = K-third
    const int l  = t0 & 63;          // lane
    const int batch = blockIdx.x;

    const int c0 = l;                // owned column 1 (0..63)
    const int c1 = 64 + l;           // owned column 2 (valid while < 100)
    const bool has1 = (l < 36);
    const int j3 = l & 31;           // P3/RK output index
    const int w1i = (w == 2) ? 0 : w + 1;
    const int w2i = (w1i == 2) ? 0 : w1i + 1;

    const int r1 = (w == 0) ? 0 : (w == 1) ? 11 : 22;   // P1 rows: 11,11,10
    const int n1 = (w == 2) ? 10 : 11;
    const int r2 = (w == 0) ? 0 : (w == 1) ? 34 : 67;   // P2/P3 rows: 34,33,33
    const int n2 = (w == 0) ? 34 : 33;

    // ---- per-wave K-third weights (124 floats max) ----
    float rw1a[11], rw1b[11], rw2a[34], rw2b[34], rw3[34];
#pragma unroll
    for (int i = 0; i < 11; ++i) {
        const bool v = (i < n1);
        rw1a[i] = v ? dw1[(r1 + i) * 100 + c0] : 0.f;
        rw1b[i] = (v && has1) ? dw1[(r1 + i) * 100 + c1] : 0.f;
    }
#pragma unroll
    for (int i = 0; i < 34; ++i) {
        const bool v = (i < n2);
        rw2a[i] = v ? dw2[(r2 + i) * 100 + c0] : 0.f;
        rw2b[i] = (v && has1) ? dw2[(r2 + i) * 100 + c1] : 0.f;
        rw3[i]  = v ? dw3[(r2 + i) * 32 + j3] : 0.f;
    }
    const float rb1a = db1[c0];
    const float rb1b = has1 ? db1[c1] : 0.f;
    const float rb2a = db2[c0];
    const float rb2b = has1 ? db2[c1] : 0.f;
    const float b3d  = db3[j3];

    for (int i = t0; i < 200; i += 192) s_t[i] = tg[i];

    float z_r = ws[WS_Z + (size_t)batch * 32 + j3];   // dup'd in all lanes/waves
    float ka_r = 0.f;
    float zs = z_r;
    __syncthreads();

    for (int s = 0; s < 200; ++s) {
        if (t0 < 32)
            ws[WS_SOL + (size_t)(s * 1024 + batch) * 32 + t0] = z_r;
        if (s == 199) break;
        const float dtv = s_t[s + 1] - s_t[s];

#pragma unroll 1
        for (int e = 0; e < 4; ++e) {
            // ---- P1 partial: z rows [r1, r1+n1) x cols {c0,c1} ----
            {
                float a0 = 0.f, a1 = 0.f;
                if (w == 0) {
#pragma unroll
                    for (int i = 0; i < 11; ++i) {
                        const float sv = bcast(zs, i);
                        a0 += sv * rw1a[i]; a1 += sv * rw1b[i];
                    }
                } else if (w == 1) {
#pragma unroll
                    for (int i = 0; i < 11; ++i) {
                        const float sv = bcast(zs, 11 + i);
                        a0 += sv * rw1a[i]; a1 += sv * rw1b[i];
                    }
                } else {
#pragma unroll
                    for (int i = 0; i < 10; ++i) {
                        const float sv = bcast(zs, 22 + i);
                        a0 += sv * rw1a[i]; a1 += sv * rw1b[i];
                    }
                }
                s_p1[w][c0] = a0;
                if (has1) s_p1[w][c1] = a1;
            }
            __syncthreads();   // barrier 1

            // ---- h1 combine (own partial in reg via re-read; use LDS sums) ----
            const float h1_0 = tanh_fast(rb1a + s_p1[0][c0] + s_p1[1][c0] + s_p1[2][c0]);
            const float h1_1 = has1 ? tanh_fast(rb1b + s_p1[0][c1] + s_p1[1][c1] + s_p1[2][c1]) : 0.f;

            // ---- P2 partial: h1 rows [r2, r2+n2) x cols {c0,c1} ----
            {
                float a2 = 0.f, a3 = 0.f;
                if (w == 0) {
#pragma unroll
                    for (int i = 0; i < 34; ++i) {
                        const float sv = bcast(h1_0, i);
                        a2 += sv * rw2a[i]; a3 += sv * rw2b[i];
                    }
                } else if (w == 1) {
#pragma unroll
                    for (int i = 0; i < 30; ++i) {          // rows 34..63 from h1_0
                        const float sv = bcast(h1_0, 34 + i);
                        a2 += sv * rw2a[i]; a3 += sv * rw2b[i];
                    }
#pragma unroll
                    for (int i = 30; i < 33; ++i) {         // rows 64..66 from h1_1
                        const float sv = bcast(h1_1, i - 30);
                        a2 += sv * rw2a[i]; a3 += sv * rw2b[i];
                    }
                } else {
#pragma unroll
                    for (int i = 0; i < 33; ++i) {          // rows 67..99 from h1_1
                        const float sv = bcast(h1_1, 3 + i);
                        a2 += sv * rw2a[i]; a3 += sv * rw2b[i];
                    }
                }
                s_p2[w][c0] = a2;
                if (has1) s_p2[w][c1] = a3;
            }
            __syncthreads();   // barrier 2

            // ---- h2 combine ----
            const float h2_0 = tanh_fast(rb2a + s_p2[0][c0] + s_p2[1][c0] + s_p2[2][c0]);
            const float h2_1 = has1 ? tanh_fast(rb2b + s_p2[0][c1] + s_p2[1][c1] + s_p2[2][c1]) : 0.f;

            // ---- P3 partial: h2 rows [r2, r2+n2) -> out j3 ----
            {
                float ap = 0.f;
                if (w == 0) {
#pragma unroll
                    for (int i = 0; i < 34; ++i) ap += bcast(h2_0, i) * rw3[i];
                } else if (w == 1) {
#pragma unroll
                    for (int i = 0; i < 30; ++i) ap += bcast(h2_0, 34 + i) * rw3[i];
#pragma unroll
                    for (int i = 30; i < 33; ++i) ap += bcast(h2_1, i - 30) * rw3[i];
                } else {
#pragma unroll
                    for (int i = 0; i < 33; ++i) ap += bcast(h2_1, 3 + i) * rw3[i];
                }
                if (l < 32) s_p3[w][l] = ap;   // both halves identical; one writes
            }
            __syncthreads();   // barrier 3

            // ---- RK combine (all lanes, state dup'd; no LDS for z) ----
            {
                const float kj = b3d + s_p3[0][j3] + s_p3[1][j3] + s_p3[2][j3];
                if (e == 0)      { ka_r = kj;        zs = z_r + 0.5f * dtv * kj; }
                else if (e == 1) { ka_r += 2.f * kj; zs = z_r + 0.5f * dtv * kj; }
                else if (e == 2) { ka_r += 2.f * kj; zs = z_r + dtv * kj; }
                else             { z_r += (dtv / 6.f) * (ka_r + kj); zs = z_r; }
            }
        }
    }
    (void)w1i; (void)w2i;
}

__global__ __launch_bounds__(256) void proj_kernel(
    const float* __restrict__ ow, const float* __restrict__ ob,
    const float* __restrict__ ws, float* __restrict__ out)
{
    const int t0 = threadIdx.x;
    const int d = t0 & 127, half = t0 >> 7;
    float rw[32];
#pragma unroll
    for (int k = 0; k < 32; ++k) rw[k] = ow[k * 128 + d];
    const float bo = ob[d];
    const int sb0 = blockIdx.x * 64 + half * 32;
#pragma unroll 2
    for (int m = 0; m < 32; ++m) {
        const int sb = sb0 + m;
        const int s = sb >> 10, b = sb & 1023;
        const float4* zp = (const float4*)&ws[WS_SOL + (size_t)sb * 32];
        float acc = bo;
#pragma unroll
        for (int kq = 0; kq < 8; ++kq) {
            const float4 zv = zp[kq];
            acc += zv.x * rw[4 * kq] + zv.y * rw[4 * kq + 1]
                 + zv.z * rw[4 * kq + 2] + zv.w * rw[4 * kq + 3];
        }
        out[((size_t)b * 200 + s) * 128 + d] = acc;
    }
}

extern "C" void kernel_launch(void* const* d_in, const int* in_sizes, int n_in,
                              void* d_out, int out_size, void* d_ws, size_t ws_size,
                              hipStream_t stream)
{
    const float* truth = (const float*)d_in[0];
    const float* tg    = (const float*)d_in[1];
    const int*   oi    = (const int*)d_in[2];
    const float* eps   = (const float*)d_in[3];
    const float* ew1   = (const float*)d_in[4];
    const float* eb1   = (const float*)d_in[5];
    const float* ew2   = (const float*)d_in[6];
    const float* eb2   = (const float*)d_in[7];
    const float* uw1   = (const float*)d_in[8];
    const float* ub1   = (const float*)d_in[9];
    const float* uw2   = (const float*)d_in[10];
    const float* ub2   = (const float*)d_in[11];
    const float* rw1   = (const float*)d_in[12];
    const float* rb1   = (const float*)d_in[13];
    const float* rw2   = (const float*)d_in[14];
    const float* rb2   = (const float*)d_in[15];
    const float* nw1   = (const float*)d_in[16];
    const float* nb1   = (const float*)d_in[17];
    const float* nw2   = (const float*)d_in[18];
    const float* nb2   = (const float*)d_in[19];
    const float* z0w1  = (const float*)d_in[20];
    const float* z0b1  = (const float*)d_in[21];
    const float* z0w2  = (const float*)d_in[22];
    const float* z0b2  = (const float*)d_in[23];
    const float* dw1   = (const float*)d_in[24];
    const float* db1   = (const float*)d_in[25];
    const float* dw2   = (const float*)d_in[26];
    const float* db2   = (const float*)d_in[27];
    const float* dw3   = (const float*)d_in[28];
    const float* db3   = (const float*)d_in[29];
    const float* ow    = (const float*)d_in[30];
    const float* ob    = (const float*)d_in[31];
    float* ws  = (float*)d_ws;
    float* out = (float*)d_out;

    prep_kernel<<<dim3(120), dim3(256), 0, stream>>>(uw1, ub1, rw1, rb1, nw1, nb1, ws);
    for (int c = 0; c < NCH; ++c) {
        hpre_gemm<<<dim3(CH * 16 * 5), dim3(256), 0, stream>>>(truth, oi, ws, ws + WS_HPRE, c * CH);
        enc_chunk<<<dim3(NWG), dim3(256), 0, stream>>>(
            tg, oi, eps, ew1, eb1, ew2, eb2, uw2, ub2, rw2, rb2, nw2, nb2,
            z0w1, z0b1, z0w2, z0b2, ws, c * CH);
    }
    dec_kernel<<<dim3(1024), dim3(192), 0, stream>>>(tg, dw1, db1, dw2, db2, dw3, db3, ws);
    proj_kernel<<<dim3(3200), dim3(256), 0, stream>>>(ow, ob, ws, out);
}

// Round 9
// 3799.554 us; speedup vs baseline: 1.1592x; 1.1592x over previous
//
#include <hip/hip_runtime.h>
#include <math.h>

// latentODE: T=200, B=1024, D=128, T_OBS=140, L=20, LAT=32, GRU_U=200, UNITS=100
// Dec history: R7 (1024blk x 2 waves, K-half split, readlane bcast, 3 barriers,
// tanh_fast) = 1203us MEASURED BEST. R8 (6 barriers) 1645, R9 (scratch) 1826,
// R10 (2-batch amortize) 1404, R11 (3-wave split) 1809. All departures from R7
// regressed -> R12 consolidates: dec reverted byte-for-byte to R7; enc keeps
// R10's tanh_fast/sigm_fast (measured -290us vs ocml).
#define BB 1024
#define DD 128
#define NWG 256
#define CH 28
#define NCH 5

// ws layout (float offsets)
#define WS_WPACK 0
#define WS_B1E   81920
#define WS_W1Y   82560
#define WS_Y     106560
#define WS_Z     147520
#define WS_HPRE  180288
#define WS_SOL   180288

__device__ __forceinline__ float bcast(float v, int lane) {
    return __uint_as_float(__builtin_amdgcn_readlane(__float_as_uint(v), lane));
}

// tanh(x) = 1 - 2/(e^{2x}+1); exp2/rcp HW approx (~1ulp), saturates correctly.
__device__ __forceinline__ float tanh_fast(float x) {
    const float t = __builtin_amdgcn_exp2f(x * 2.88539008177793f);
    return 1.f - 2.f * __builtin_amdgcn_rcpf(t + 1.f);
}
// sigmoid(x) = 1/(1+e^-x), exp2/rcp form; saturates to {0,1} correctly.
__device__ __forceinline__ float sigm_fast(float x) {
    const float t = __builtin_amdgcn_exp2f(x * -1.4426950408889634f);
    return __builtin_amdgcn_rcpf(1.f + t);
}

__global__ __launch_bounds__(256) void prep_kernel(
    const float* __restrict__ uw1, const float* __restrict__ ub1,
    const float* __restrict__ rw1, const float* __restrict__ rb1,
    const float* __restrict__ nw1, const float* __restrict__ nb1,
    float* __restrict__ ws)
{
    int tid = blockIdx.x * blockDim.x + threadIdx.x;
    int nth = gridDim.x * blockDim.x;
    for (int idx = tid; idx < 128 * 640; idx += nth) {
        int k = idx / 640, j = idx - k * 640;
        float v = 0.f;
        if (j < 600) {
            int g = j / 200, jj = j - g * 200;
            const float* w1 = (g == 0) ? uw1 : (g == 1) ? rw1 : nw1;
            v = w1[(40 + k) * 200 + jj];
        }
        ws[WS_WPACK + idx] = v;
    }
    for (int j = tid; j < 640; j += nth) {
        float s = 0.f;
        if (j < 600) {
            int g = j / 200, jj = j - g * 200;
            const float* w1 = (g == 0) ? uw1 : (g == 1) ? rw1 : nw1;
            const float* b1 = (g == 0) ? ub1 : (g == 1) ? rb1 : nb1;
            s = b1[jj];
            for (int k = 168; k < 296; ++k) s += w1[k * 200 + jj];
        }
        ws[WS_B1E + j] = s;
    }
    for (int idx = tid; idx < 40 * 600; idx += nth) {
        int k = idx / 600, j = idx - k * 600;
        int g = j / 200, jj = j - g * 200;
        const float* w1 = (g == 0) ? uw1 : (g == 1) ? rw1 : nw1;
        ws[WS_W1Y + idx] = w1[k * 200 + jj];
    }
}

__global__ __launch_bounds__(256) void hpre_gemm(
    const float* __restrict__ truth, const int* __restrict__ obs_idx,
    const float* __restrict__ ws, float* __restrict__ hpre, int s0)
{
    __shared__ float sx[64][68];
    __shared__ float sw[64][132];
    const int t0 = threadIdx.x;
    const int jt = blockIdx.x % 5;
    const int bt = (blockIdx.x / 5) % 16;
    const int sl = blockIdx.x / 80;
    const int oi = obs_idx[139 - (s0 + sl)];
    const int b0 = bt * 64;
    const float* wpack = ws + WS_WPACK;
    const float* b1e   = ws + WS_B1E;

    const int jj  = t0 & 15;
    const int bb4 = t0 >> 4;
    float acc[8][4];
#pragma unroll
    for (int m = 0; m < 8; ++m)
#pragma unroll
        for (int q = 0; q < 4; ++q) acc[m][q] = 0.f;

    for (int kh = 0; kh < 2; ++kh) {
        __syncthreads();
        for (int i = t0; i < 64 * 16; i += 256) {
            int bb = i >> 4, kq = i & 15;
            const float4 v = *(const float4*)&truth[((size_t)oi * BB + b0 + bb) * DD + kh * 64 + kq * 4];
            *(float4*)&sx[bb][kq * 4] = v;
        }
        for (int i = t0; i < 64 * 32; i += 256) {
            int kk = i >> 5, jq = i & 31;
            const float4 v = *(const float4*)&wpack[(kh * 64 + kk) * 640 + jt * 128 + jq * 4];
            *(float4*)&sw[kk][jq * 4] = v;
        }
        __syncthreads();
#pragma unroll 4
        for (int k = 0; k < 64; ++k) {
            float xv[4], wv[8];
#pragma unroll
            for (int q = 0; q < 4; ++q) xv[q] = sx[bb4 * 4 + q][k];
#pragma unroll
            for (int m = 0; m < 8; ++m) wv[m] = sw[k][jj + 16 * m];
#pragma unroll
            for (int m = 0; m < 8; ++m)
#pragma unroll
                for (int q = 0; q < 4; ++q) acc[m][q] += wv[m] * xv[q];
        }
    }
    const int bblk = bt * 16 + bb4;
#pragma unroll
    for (int m = 0; m < 8; ++m) {
        int j = jt * 128 + jj + 16 * m;
        if (j < 600) {
            float be = b1e[j];
#pragma unroll
            for (int q = 0; q < 4; ++q)
                hpre[(size_t)((sl * 256 + bblk) * 4 + q) * 600 + j] = acc[m][q] + be;
        }
    }
}

__global__ __launch_bounds__(256, 1) void enc_chunk(
    const float* __restrict__ tg, const int* __restrict__ obs_idx,
    const float* __restrict__ eps,
    const float* __restrict__ ew1, const float* __restrict__ eb1,
    const float* __restrict__ ew2, const float* __restrict__ eb2,
    const float* __restrict__ uw2, const float* __restrict__ ub2,
    const float* __restrict__ rw2, const float* __restrict__ rb2,
    const float* __restrict__ nw2, const float* __restrict__ nb2,
    const float* __restrict__ z0w1, const float* __restrict__ z0b1,
    const float* __restrict__ z0w2, const float* __restrict__ z0b2,
    float* __restrict__ ws, int s0)
{
    __shared__ float s_t[200];
    __shared__ int   s_oi[140];
    __shared__ __align__(16) float s_y[40][4];      // [k][b]
    __shared__ __align__(16) float s_ytmp[20][4];
    __shared__ float s_kacc[20][4];
    __shared__ __align__(16) float s_hid[4][104];   // pads 100..103 = 0
    __shared__ float s_pe[20][4][2];
    __shared__ __align__(16) float s_ew1t[100 * 20];   // [c][k]
    __shared__ __align__(16) float s_w2n[40 * 212];    // [o][k], k>=200 zero
    __shared__ __align__(16) float s_hur[4][416];      // u: [0..207], r: [208..415]
    __shared__ __align__(16) float s_hn[4][208];       // pads 200..207 = 0
    __shared__ float s_pw[80][4][4];
    __shared__ float s_pn[40][4][4];
    __shared__ float s_u[40][4];
    __shared__ __align__(16) float s_yr[40][4];
    __shared__ float s_z0o[4][64];

    const int t0 = threadIdx.x;
    const int bblk = blockIdx.x;
    const int b0 = bblk * 4;
    const float* hpre = ws + WS_HPRE;

    // ---- register weights (roles; worst-case union ~280 VGPR, fits (256,1)) ----
    float rgy[3][40];     // t<200: W1y cols {u_j, r_j, n_j}
    float rew2h[52];      // t<160: RK stage2 K-half
    float rw2q[2][52];    // t<160: W2 u/r quarter, two outs same gate
    float eb1_r = 0.f, eb2_r = 0.f, bur_r = 0.f, bn_r = 0.f;

    if (t0 < 200) {
#pragma unroll
        for (int g = 0; g < 3; ++g)
#pragma unroll
            for (int k = 0; k < 40; ++k)
                rgy[g][k] = ws[WS_W1Y + k * 600 + g * 200 + t0];
    }
    if (t0 < 100) eb1_r = eb1[t0];
    if (t0 < 160) {
        const int c2 = t0 % 20, kh = t0 / 80;
#pragma unroll
        for (int i = 0; i < 52; ++i) {
            const int row = kh * 52 + i;
            rew2h[i] = (row < 100) ? ew2[row * 20 + c2] : 0.f;
        }
    }
    if (t0 < 80) eb2_r = eb2[t0 % 20];
    if (t0 < 160) {
        const int p = t0 % 20, g = (t0 / 20) % 2, kq = t0 / 40;
        const float* w2 = g ? rw2 : uw2;
#pragma unroll
        for (int j = 0; j < 2; ++j)
#pragma unroll
            for (int i = 0; i < 52; ++i) {
                const int row = kq * 52 + i;
                rw2q[j][i] = (row < 200) ? w2[row * 40 + p + 20 * j] : 0.f;
            }
        bur_r = ((t0 % 80) < 40) ? ub2[t0 % 80] : rb2[(t0 % 80) - 40];
        bn_r = nb2[t0 % 40];
    }

    for (int i = t0; i < 2000; i += 256) { int k = i / 100, c = i % 100; s_ew1t[c * 20 + k] = ew1[i]; }
    for (int i = t0; i < 40 * 212; i += 256) { int o = i / 212, k = i % 212; s_w2n[i] = (k < 200) ? nw2[k * 40 + o] : 0.f; }
    for (int i = t0; i < 200; i += 256) s_t[i] = tg[i];
    for (int i = t0; i < 140; i += 256) s_oi[i] = obs_idx[i];
    if (t0 < 160) { int k = t0 % 40, b = t0 / 40; s_y[k][b] = s0 ? ws[WS_Y + k * 1024 + b0 + b] : 0.f; }
    if (t0 < 4) {
#pragma unroll
        for (int i = 0; i < 4; ++i) s_hid[t0][100 + i] = 0.f;
#pragma unroll
        for (int i = 0; i < 8; ++i) { s_hur[t0][200 + i] = 0.f; s_hur[t0][408 + i] = 0.f; s_hn[t0][200 + i] = 0.f; }
    }
    __syncthreads();

    for (int sl = 0; sl < CH; ++sl) {
        const int s = s0 + sl;
        const int oi = s_oi[139 - s];
        const float dt = (s == 0) ? 0.f : (s_t[oi] - s_t[s_oi[140 - s]]);

        float hpu[4], hpr[4], hpn[4];
        if (t0 < 200) {
#pragma unroll
            for (int q = 0; q < 4; ++q) {
                const size_t r = (size_t)((sl * 256 + bblk) * 4 + q) * 600;
                hpu[q] = hpre[r + t0];
                hpr[q] = hpre[r + 200 + t0];
                hpn[q] = hpre[r + 400 + t0];
            }
        }

        // ---- RK4 on ym (enc_f: 20 -> 100 -> 20) ----
#pragma unroll 1
        for (int e = 0; e < 4; ++e) {
            if (t0 < 100) {
                const int c = t0;
                float a[4] = {eb1_r, eb1_r, eb1_r, eb1_r};
#pragma unroll
                for (int i = 0; i < 5; ++i) {
                    const float4 wv = *(const float4*)&s_ew1t[c * 20 + 4 * i];
                    const float wk[4] = {wv.x, wv.y, wv.z, wv.w};
#pragma unroll
                    for (int kk = 0; kk < 4; ++kk) {
                        const int k = 4 * i + kk;
                        const float4 yv = (e == 0) ? *(const float4*)&s_y[k][0]
                                                   : *(const float4*)&s_ytmp[k][0];
                        a[0] += wk[kk] * yv.x; a[1] += wk[kk] * yv.y;
                        a[2] += wk[kk] * yv.z; a[3] += wk[kk] * yv.w;
                    }
                }
#pragma unroll
                for (int b = 0; b < 4; ++b) s_hid[b][c] = tanh_fast(a[b]);
            }
            __syncthreads();
            if (t0 < 160) {
                const int c2 = t0 % 20, b = (t0 / 20) % 4, kh = t0 / 80;
                float acc = 0.f;
#pragma unroll
                for (int i = 0; i < 13; ++i) {
                    const float4 hv = *(const float4*)&s_hid[b][kh * 52 + 4 * i];
                    acc += hv.x * rew2h[4 * i] + hv.y * rew2h[4 * i + 1]
                         + hv.z * rew2h[4 * i + 2] + hv.w * rew2h[4 * i + 3];
                }
                s_pe[c2][b][kh] = acc;
            }
            __syncthreads();
            if (t0 < 80) {
                const int c2 = t0 % 20, b = t0 / 20;
                const float kv = eb2_r + s_pe[c2][b][0] + s_pe[c2][b][1];
                const float y0 = s_y[c2][b];
                if (e == 0)      { s_kacc[c2][b] = kv;        s_ytmp[c2][b] = y0 + 0.5f * dt * kv; }
                else if (e == 1) { s_kacc[c2][b] += 2.f * kv; s_ytmp[c2][b] = y0 + 0.5f * dt * kv; }
                else if (e == 2) { s_kacc[c2][b] += 2.f * kv; s_ytmp[c2][b] = y0 + dt * kv; }
                else             { s_y[c2][b] = y0 + (dt / 6.f) * (s_kacc[c2][b] + kv); }
            }
            __syncthreads();
        }

        // ---- B: u/r hidden = tanh(hpre + y @ W1y) ----
        if (t0 < 200) {
            float au[4], ar[4];
#pragma unroll
            for (int b = 0; b < 4; ++b) { au[b] = hpu[b]; ar[b] = hpr[b]; }
#pragma unroll
            for (int k = 0; k < 40; ++k) {
                const float4 yv = *(const float4*)&s_y[k][0];
                const float wu = rgy[0][k], wr = rgy[1][k];
                au[0] += wu * yv.x; au[1] += wu * yv.y; au[2] += wu * yv.z; au[3] += wu * yv.w;
                ar[0] += wr * yv.x; ar[1] += wr * yv.y; ar[2] += wr * yv.z; ar[3] += wr * yv.w;
            }
#pragma unroll
            for (int b = 0; b < 4; ++b) {
                s_hur[b][t0] = tanh_fast(au[b]);
                s_hur[b][208 + t0] = tanh_fast(ar[b]);
            }
        }
        __syncthreads();

        // ---- W2 u/r partials: (p,g,kq) -> outs {g_p, g_{p+20}}, K-quarter ----
        if (t0 < 160) {
            const int p = t0 % 20, g = (t0 / 20) % 2, kq = t0 / 40;
            const int goff = g * 208;
            float a1[4] = {0.f, 0.f, 0.f, 0.f}, a2[4] = {0.f, 0.f, 0.f, 0.f};
#pragma unroll
            for (int i = 0; i < 13; ++i) {
                const float wa = rw2q[0][4 * i], wb = rw2q[0][4 * i + 1],
                            wc = rw2q[0][4 * i + 2], wd = rw2q[0][4 * i + 3];
                const float we = rw2q[1][4 * i], wf = rw2q[1][4 * i + 1],
                            wg = rw2q[1][4 * i + 2], wh = rw2q[1][4 * i + 3];
#pragma unroll
                for (int b = 0; b < 4; ++b) {
                    const float4 hv = *(const float4*)&s_hur[b][goff + kq * 52 + 4 * i];
                    a1[b] += hv.x * wa + hv.y * wb + hv.z * wc + hv.w * wd;
                    a2[b] += hv.x * we + hv.y * wf + hv.z * wg + hv.w * wh;
                }
            }
            const int o1 = 40 * g + p, o2 = o1 + 20;
#pragma unroll
            for (int b = 0; b < 4; ++b) { s_pw[o1][b][kq] = a1[b]; s_pw[o2][b][kq] = a2[b]; }
        }
        __syncthreads();

        // ---- u/r reduce: sigmoid; u and yr = y*r ----
        if (t0 < 160) {
            const int o = t0 % 80, bp = t0 / 80;
#pragma unroll
            for (int j = 0; j < 2; ++j) {
                const int b = 2 * bp + j;
                const float v = bur_r + s_pw[o][b][0] + s_pw[o][b][1] + s_pw[o][b][2] + s_pw[o][b][3];
                const float sg = sigm_fast(v);
                if (o < 40) s_u[o][b] = sg;
                else        s_yr[o - 40][b] = s_y[o - 40][b] * sg;
            }
        }
        __syncthreads();

        // ---- C: n hidden = tanh(hpre_n + yr @ W1ny) ----
        if (t0 < 200) {
            float an[4];
#pragma unroll
            for (int b = 0; b < 4; ++b) an[b] = hpn[b];
#pragma unroll
            for (int k = 0; k < 40; ++k) {
                const float4 yv = *(const float4*)&s_yr[k][0];
                const float w = rgy[2][k];
                an[0] += w * yv.x; an[1] += w * yv.y; an[2] += w * yv.z; an[3] += w * yv.w;
            }
#pragma unroll
            for (int b = 0; b < 4; ++b) s_hn[b][t0] = tanh_fast(an[b]);
        }
        __syncthreads();

        // ---- W2n partials (weights from LDS, stride 212 = 4*odd) ----
        if (t0 < 160) {
            const int o = t0 % 40, kq = t0 / 40;
            float an[4] = {0.f, 0.f, 0.f, 0.f};
#pragma unroll
            for (int i = 0; i < 13; ++i) {
                const float4 wv = *(const float4*)&s_w2n[o * 212 + kq * 52 + 4 * i];
#pragma unroll
                for (int b = 0; b < 4; ++b) {
                    const float4 hv = *(const float4*)&s_hn[b][kq * 52 + 4 * i];
                    an[b] += hv.x * wv.x + hv.y * wv.y + hv.z * wv.z + hv.w * wv.w;
                }
            }
#pragma unroll
            for (int b = 0; b < 4; ++b) s_pn[o][b][kq] = an[b];
        }
        __syncthreads();

        // ---- n reduce + state update ----
        if (t0 < 160) {
            const int o = t0 % 40, b = t0 / 40;
            const float v = bn_r + s_pn[o][b][0] + s_pn[o][b][1] + s_pn[o][b][2] + s_pn[o][b][3];
            const float cand = (o < 20) ? v : fabsf(v);
            const float uu = s_u[o][b];
            s_y[o][b] = (1.f - uu) * cand + uu * s_y[o][b];
        }
        __syncthreads();
    }

    // ---- z0 head (last chunk) ----
    if (s0 + CH == 140) {
        if (t0 < 100) {
            const int c = t0;
            float a[4] = {z0b1[c], z0b1[c], z0b1[c], z0b1[c]};
#pragma unroll
            for (int k = 0; k < 40; ++k) {
                const float4 yv = *(const float4*)&s_y[k][0];
                const float w = z0w1[k * 100 + c];
                a[0] += w * yv.x; a[1] += w * yv.y; a[2] += w * yv.z; a[3] += w * yv.w;
            }
#pragma unroll
            for (int b = 0; b < 4; ++b) s_hid[b][c] = tanh_fast(a[b]);
        }
        __syncthreads();
        {
            const int b = t0 / 64, u = t0 % 64;
            float acc = z0b2[u];
#pragma unroll
            for (int i = 0; i < 25; ++i) {
                const float4 hv = *(const float4*)&s_hid[b][4 * i];
                acc += hv.x * z0w2[(4 * i) * 64 + u] + hv.y * z0w2[(4 * i + 1) * 64 + u]
                     + hv.z * z0w2[(4 * i + 2) * 64 + u] + hv.w * z0w2[(4 * i + 3) * 64 + u];
            }
            s_z0o[b][u] = acc;
        }
        __syncthreads();
        if (t0 < 128) {
            const int b = t0 / 32, i = t0 % 32;
            const int gb = b0 + b;
            ws[WS_Z + gb * 32 + i] = s_z0o[b][i] + eps[gb * 32 + i] * fabsf(s_z0o[b][32 + i]);
        }
    }
    if (t0 < 160) {
        const int k = t0 % 40, b = t0 / 40;
        ws[WS_Y + k * 1024 + b0 + b] = s_y[k][b];
    }
}

// R12 dec = R7 dec verbatim (measured 1203us): 1024 blocks x 128 threads
// (2 waves), ONE BATCH PER BLOCK. Wave w owns K-slice {P1: rows 16w..16w+16,
// P2/P3: rows 50w..50w+50}. Per-wave weights 182 floats; readlane broadcast
// with literal indices inside wave-uniform branches; cross-wave combine 2 LDS
// floats/phase + 3 barriers/eval; z dup'd per half-wave; fast tanh.
__global__ __launch_bounds__(128, 2) void dec_kernel(
    const float* __restrict__ tg,
    const float* __restrict__ dw1, const float* __restrict__ db1,
    const float* __restrict__ dw2, const float* __restrict__ db2,
    const float* __restrict__ dw3, const float* __restrict__ db3,
    float* __restrict__ ws)
{
    __shared__ float s_t[200];
    __shared__ float s_p1[2][100];
    __shared__ float s_p2[2][100];
    __shared__ float s_p3[2][32];

    const int t0 = threadIdx.x;
    const int w  = t0 >> 6;          // wave = K-slice
    const int l  = t0 & 63;          // lane
    const int batch = blockIdx.x;

    const int c0 = l;                // owned column 1 (0..63)
    const int c1 = 64 + l;           // owned column 2 (valid while < 100)
    const bool has1 = (l < 36);
    const int j3 = l & 31;           // phase3 output (dup'd across halves+waves)

    // ---- per-wave K-slice weights, VGPR-resident ----
    float rw1a[16], rw1b[16], rw2a[50], rw2b[50], rw3[50];
#pragma unroll
    for (int i = 0; i < 16; ++i) {
        rw1a[i] = dw1[(16 * w + i) * 100 + c0];
        rw1b[i] = has1 ? dw1[(16 * w + i) * 100 + c1] : 0.f;
    }
#pragma unroll
    for (int i = 0; i < 50; ++i) {
        rw2a[i] = dw2[(50 * w + i) * 100 + c0];
        rw2b[i] = has1 ? dw2[(50 * w + i) * 100 + c1] : 0.f;
        rw3[i]  = dw3[(50 * w + i) * 32 + j3];
    }
    const float rb1a = db1[c0];
    const float rb1b = has1 ? db1[c1] : 0.f;
    const float rb2a = db2[c0];
    const float rb2b = has1 ? db2[c1] : 0.f;
    const float rb3  = db3[j3];

    for (int i = t0; i < 200; i += 128) s_t[i] = tg[i];

    float z_r = ws[WS_Z + (size_t)batch * 32 + j3];   // dup'd across halves/waves
    __syncthreads();

    float zs = z_r, ka_r = 0.f;

    for (int s = 0; s < 200; ++s) {
        if (t0 < 32)
            ws[WS_SOL + (size_t)(s * 1024 + batch) * 32 + l] = z_r;
        if (s == 199) break;
        const float dtv = s_t[s + 1] - s_t[s];

#pragma unroll 1
        for (int e = 0; e < 4; ++e) {
            // ---- P1 partial: zs @ dw1 over K-slice [16w, 16w+16) ----
            float a0 = 0.f, a1 = 0.f;
            if (w == 0) {
#pragma unroll
                for (int i = 0; i < 16; ++i) {
                    const float sv = bcast(zs, i);
                    a0 += sv * rw1a[i]; a1 += sv * rw1b[i];
                }
            } else {
#pragma unroll
                for (int i = 0; i < 16; ++i) {
                    const float sv = bcast(zs, 16 + i);
                    a0 += sv * rw1a[i]; a1 += sv * rw1b[i];
                }
            }
            s_p1[w][c0] = a0;
            if (has1) s_p1[w][c1] = a1;
            __syncthreads();
            const float h1_0 = tanh_fast(rb1a + a0 + s_p1[w ^ 1][c0]);
            const float h1_1 = has1 ? tanh_fast(rb1b + a1 + s_p1[w ^ 1][c1]) : 0.f;

            // ---- P2 partial: h1 @ dw2 over K-slice [50w, 50w+50) ----
            float a2 = 0.f, a3 = 0.f;
            if (w == 0) {
#pragma unroll
                for (int i = 0; i < 50; ++i) {
                    const float sv = bcast(h1_0, i);
                    a2 += sv * rw2a[i]; a3 += sv * rw2b[i];
                }
            } else {
#pragma unroll
                for (int i = 0; i < 14; ++i) {          // k = 50..63 from h1_0
                    const float sv = bcast(h1_0, 50 + i);
                    a2 += sv * rw2a[i]; a3 += sv * rw2b[i];
                }
#pragma unroll
                for (int i = 14; i < 50; ++i) {         // k = 64..99 from h1_1
                    const float sv = bcast(h1_1, i - 14);
                    a2 += sv * rw2a[i]; a3 += sv * rw2b[i];
                }
            }
            s_p2[w][c0] = a2;
            if (has1) s_p2[w][c1] = a3;
            __syncthreads();
            const float h2_0 = tanh_fast(rb2a + a2 + s_p2[w ^ 1][c0]);
            const float h2_1 = has1 ? tanh_fast(rb2b + a3 + s_p2[w ^ 1][c1]) : 0.f;

            // ---- P3 partial: h2 @ dw3 over K-slice (out j3, dup'd halves) ----
            float ap = 0.f;
            if (w == 0) {
#pragma unroll
                for (int i = 0; i < 50; ++i) ap += bcast(h2_0, i) * rw3[i];
            } else {
#pragma unroll
                for (int i = 0; i < 14; ++i) ap += bcast(h2_0, 50 + i) * rw3[i];
#pragma unroll
                for (int i = 14; i < 50; ++i) ap += bcast(h2_1, i - 14) * rw3[i];
            }
            if (l < 32) s_p3[w][l] = ap;
            __syncthreads();
            const float kj = rb3 + s_p3[0][j3] + s_p3[1][j3];

            // ---- RK combine (all lanes, state dup'd) ----
            if (e == 0)      { ka_r = kj;        zs = z_r + 0.5f * dtv * kj; }
            else if (e == 1) { ka_r += 2.f * kj; zs = z_r + 0.5f * dtv * kj; }
            else if (e == 2) { ka_r += 2.f * kj; zs = z_r + dtv * kj; }
            else             { z_r += (dtv / 6.f) * (ka_r + kj); zs = z_r; }
        }
    }
}

__global__ __launch_bounds__(256) void proj_kernel(
    const float* __restrict__ ow, const float* __restrict__ ob,
    const float* __restrict__ ws, float* __restrict__ out)
{
    const int t0 = threadIdx.x;
    const int d = t0 & 127, half = t0 >> 7;
    float rw[32];
#pragma unroll
    for (int k = 0; k < 32; ++k) rw[k] = ow[k * 128 + d];
    const float bo = ob[d];
    const int sb0 = blockIdx.x * 64 + half * 32;
#pragma unroll 2
    for (int m = 0; m < 32; ++m) {
        const int sb = sb0 + m;
        const int s = sb >> 10, b = sb & 1023;
        const float4* zp = (const float4*)&ws[WS_SOL + (size_t)sb * 32];
        float acc = bo;
#pragma unroll
        for (int kq = 0; kq < 8; ++kq) {
            const float4 zv = zp[kq];
            acc += zv.x * rw[4 * kq] + zv.y * rw[4 * kq + 1]
                 + zv.z * rw[4 * kq + 2] + zv.w * rw[4 * kq + 3];
        }
        out[((size_t)b * 200 + s) * 128 + d] = acc;
    }
}

extern "C" void kernel_launch(void* const* d_in, const int* in_sizes, int n_in,
                              void* d_out, int out_size, void* d_ws, size_t ws_size,
                              hipStream_t stream)
{
    const float* truth = (const float*)d_in[0];
    const float* tg    = (const float*)d_in[1];
    const int*   oi    = (const int*)d_in[2];
    const float* eps   = (const float*)d_in[3];
    const float* ew1   = (const float*)d_in[4];
    const float* eb1   = (const float*)d_in[5];
    const float* ew2   = (const float*)d_in[6];
    const float* eb2   = (const float*)d_in[7];
    const float* uw1   = (const float*)d_in[8];
    const float* ub1   = (const float*)d_in[9];
    const float* uw2   = (const float*)d_in[10];
    const float* ub2   = (const float*)d_in[11];
    const float* rw1   = (const float*)d_in[12];
    const float* rb1   = (const float*)d_in[13];
    const float* rw2   = (const float*)d_in[14];
    const float* rb2   = (const float*)d_in[15];
    const float* nw1   = (const float*)d_in[16];
    const float* nb1   = (const float*)d_in[17];
    const float* nw2   = (const float*)d_in[18];
    const float* nb2   = (const float*)d_in[19];
    const float* z0w1  = (const float*)d_in[20];
    const float* z0b1  = (const float*)d_in[21];
    const float* z0w2  = (const float*)d_in[22];
    const float* z0b2  = (const float*)d_in[23];
    const float* dw1   = (const float*)d_in[24];
    const float* db1   = (const float*)d_in[25];
    const float* dw2   = (const float*)d_in[26];
    const float* db2   = (const float*)d_in[27];
    const float* dw3   = (const float*)d_in[28];
    const float* db3   = (const float*)d_in[29];
    const float* ow    = (const float*)d_in[30];
    const float* ob    = (const float*)d_in[31];
    float* ws  = (float*)d_ws;
    float* out = (float*)d_out;

    prep_kernel<<<dim3(120), dim3(256), 0, stream>>>(uw1, ub1, rw1, rb1, nw1, nb1, ws);
    for (int c = 0; c < NCH; ++c) {
        hpre_gemm<<<dim3(CH * 16 * 5), dim3(256), 0, stream>>>(truth, oi, ws, ws + WS_HPRE, c * CH);
        enc_chunk<<<dim3(NWG), dim3(256), 0, stream>>>(
            tg, oi, eps, ew1, eb1, ew2, eb2, uw2, ub2, rw2, rb2, nw2, nb2,
            z0w1, z0b1, z0w2, z0b2, ws, c * CH);
    }
    dec_kernel<<<dim3(1024), dim3(128), 0, stream>>>(tg, dw1, db1, dw2, db2, dw3, db3, ws);
    proj_kernel<<<dim3(3200), dim3(256), 0, stream>>>(ow, ob, ws, out);
}